// Round 7
// baseline (39.036 us; speedup 1.0000x reference)
//
#include <hip/hip_runtime.h>

#define NB    64
#define NPT   8192
#define GSZ   128
#define TPB   512
#define BPB   16                         // blocks per batch
#define NBLK  (NB * BPB)                 // 1024 = 4 blk/CU * 256 CU, all co-resident
#define POISON 0xAAAAAAAAu

// Per-point permutohedral computation. Bitwise-replicates XLA-CPU f32
// (verified absmax == 0.0 rounds 1-6):
//  - pc = x*190.0f; elevated = E @ pc (FMA chain); u = rint(ev/3) (half-even)
// Integer tail exact: bin i = u0 - min_batch(u0); window <=> i<128.
__device__ __forceinline__ void compute_u(const float* __restrict__ x, int b, int n,
                                          int& u0o, int& u1o) {
    const float s6 = (float)2.449489742783178098197284074705891391989;
    const float ca = 2.0f / s6;
    const float cb = -1.0f / s6;
    const float* xb = x + (size_t)b * 6 * NPT + n;
    float p0 = xb[0 * NPT] * 190.0f;
    float p1 = xb[1 * NPT] * 190.0f;
    float p2 = xb[2 * NPT] * 190.0f;
    float ev0 = __builtin_fmaf(cb, p2, __builtin_fmaf(cb, p1, ca * p0));
    float ev1 = __builtin_fmaf(cb, p2, __builtin_fmaf(ca, p1, cb * p0));
    float ev2 = __builtin_fmaf(ca, p2, __builtin_fmaf(cb, p1, cb * p0));
    float q0 = ev0 / 3.0f, q1 = ev1 / 3.0f, q2 = ev2 / 3.0f;
    float rg0 = rintf(q0), rg1 = rintf(q1), rg2 = rintf(q2);
    int u0 = (int)rg0, u1 = (int)rg1, u2 = (int)rg2;
    float e0 = ev0 - rg0 * 3.0f;
    float e1 = ev1 - rg1 * 3.0f;
    float e2 = ev2 - rg2 * 3.0f;
    int rk0 = (int)(e1 > e0) + (int)(e2 > e0);
    int rk1 = (int)(e0 > e1) + (int)(e0 == e1) + (int)(e2 > e1);
    int rs = u0 + u1 + u2;
    if (rs > 0) {
        if (rk0 >= 3 - rs) u0 -= 1;
        if (rk1 >= 3 - rs) u1 -= 1;
    } else if (rs < 0) {
        if (rk0 < -rs) u0 += 1;
        if (rk1 < -rs) u1 += 1;
    }
    u0o = u0; u1o = u1;
}

// ws layout (uint): [0..1023] per-block packed min slots (overwritten every
// call before being read); [1024..1087] per-batch monotonic arrival counters
// (never reset; bases kept ≡0 mod 16; poison call detected & re-aligned).
__global__ __launch_bounds__(TPB, 8) void kone(const float* __restrict__ x,
                                               float* __restrict__ out,
                                               unsigned* __restrict__ ws) {
    const int bid = blockIdx.x, t = threadIdx.x;
    const int b = bid >> 4, r = bid & 15;

    // 1) zero OWN batch's slice chunk with agent-scope stores (write-through
    //    past this XCD's L2 -> visible to device-scope atomics; no wbl2 needed)
    float* zb = out + (size_t)b * 3 * GSZ * GSZ + r * 3072;
#pragma unroll
    for (int i = 0; i < 6; ++i)
        __hip_atomic_store(&zb[t + i * TPB], 0.0f, __ATOMIC_RELAXED, __HIP_MEMORY_SCOPE_AGENT);

    // 2) this block's 512 points (one per thread), block-min of (u0,u1)
    const int n = (r << 9) | t;
    int u0, u1;
    compute_u(x, b, n, u0, u1);
    int m0 = u0, m1 = u1;
    for (int o = 32; o; o >>= 1) {
        m0 = min(m0, __shfl_down(m0, o));
        m1 = min(m1, __shfl_down(m1, o));
    }
    __shared__ int red0[8], red1[8];
    __shared__ int osh[2];
    __shared__ int fallback;
    if ((t & 63) == 0) { red0[t >> 6] = m0; red1[t >> 6] = m1; }
    __syncthreads();   // drains every wave's zero-stores (vmcnt(0) before s_barrier)

    // 3) per-batch barrier: slot store + release-add, t0 spins
    if (t == 0) {
        int a0 = red0[0], a1 = red1[0];
#pragma unroll
        for (int i = 1; i < 8; ++i) { a0 = min(a0, red0[i]); a1 = min(a1, red1[i]); }
        unsigned packed = ((unsigned)(a0 + 2048) << 12) | (unsigned)(a1 + 2048);
        __hip_atomic_store(&ws[bid], packed, __ATOMIC_RELAXED, __HIP_MEMORY_SCOPE_AGENT);
        unsigned* ctr = &ws[1024 + b];
        unsigned old = __hip_atomic_fetch_add(ctr, 1u, __ATOMIC_RELEASE, __HIP_MEMORY_SCOPE_AGENT);
        unsigned base = (old - POISON < 16u) ? POISON : (old & ~15u);
        fallback = 0;
        int it = 0;
        while (__hip_atomic_load(ctr, __ATOMIC_ACQUIRE, __HIP_MEMORY_SCOPE_AGENT) - base < 16u) {
            __builtin_amdgcn_s_sleep(2);
            if (++it > (1 << 15)) { fallback = 1; break; }   // weird init -> self-compute
        }
        if (!fallback) {
            int A0 = 0x7fffffff, A1 = 0x7fffffff;
#pragma unroll
            for (int i = 0; i < 16; ++i) {
                unsigned p = __hip_atomic_load(&ws[(b << 4) + i], __ATOMIC_RELAXED, __HIP_MEMORY_SCOPE_AGENT);
                A0 = min(A0, (int)((p >> 12) & 0xFFFu) - 2048);
                A1 = min(A1, (int)(p & 0xFFFu) - 2048);
            }
            osh[0] = A0; osh[1] = A1;
        }
        if (old == POISON + 15u)  // re-align counter to ≡0 mod 16 after poison call
            __hip_atomic_fetch_add(ctr, 6u, __ATOMIC_RELAXED, __HIP_MEMORY_SCOPE_AGENT);
    }
    __syncthreads();

    if (fallback) {  // pathological first-call state: compute batch min locally
        int a0 = 0x7fffffff, a1 = 0x7fffffff;
        for (int m = t; m < NPT; m += TPB) {
            int v0, v1;
            compute_u(x, b, m, v0, v1);
            a0 = min(a0, v0); a1 = min(a1, v1);
        }
        for (int o = 32; o; o >>= 1) {
            a0 = min(a0, __shfl_down(a0, o));
            a1 = min(a1, __shfl_down(a1, o));
        }
        if ((t & 63) == 0) { red0[t >> 6] = a0; red1[t >> 6] = a1; }
        __syncthreads();
        if (t == 0) {
            int A0 = red0[0], A1 = red1[0];
#pragma unroll
            for (int i = 1; i < 8; ++i) { A0 = min(A0, red0[i]); A1 = min(A1, red1[i]); }
            osh[0] = A0; osh[1] = A1;
        }
        __syncthreads();
    }

    // 4) scatter from registers (device-scope atomics execute at the coherent
    //    point, consistent with the sc1 zeros; i,j >= 0 always)
    const int i = u0 - osh[0], j = u1 - osh[1];
    if (i < GSZ && j < GSZ) {
        const float* xb = x + (size_t)b * 6 * NPT + n;
        float* o = out + (size_t)b * 3 * GSZ * GSZ + (size_t)i * GSZ + j;
        atomicAdd(o + 0 * GSZ * GSZ, xb[3 * NPT]);
        atomicAdd(o + 1 * GSZ * GSZ, xb[4 * NPT]);
        atomicAdd(o + 2 * GSZ * GSZ, xb[5 * NPT]);
    }
}

extern "C" void kernel_launch(void* const* d_in, const int* in_sizes, int n_in,
                              void* d_out, int out_size, void* d_ws, size_t ws_size,
                              hipStream_t stream) {
    const float* x = (const float*)d_in[0];
    float* out = (float*)d_out;
    unsigned* ws = (unsigned*)d_ws;  // 1088 uints
    kone<<<NBLK, TPB, 0, stream>>>(x, out, ws);
}

// Round 8
// 14.205 us; speedup vs baseline: 2.7481x; 2.7481x over previous
//
#include <hip/hip_runtime.h>

#define NB    64
#define NPT   8192
#define GSZ   128
#define TPB   1024
#define BPB   4                       // blocks per batch
#define NBLK  (NB * BPB)              // 256 = 1 block/CU, full chip
#define ROWS  32                      // output stripe rows per block
#define PPT   (NPT / TPB)             // 8 points per thread
#define TILE  (3 * ROWS * GSZ)        // 12288 floats = 48 KB LDS

// Per-point permutohedral computation. Bitwise-replicates XLA-CPU f32
// (verified absmax == 0.0 rounds 1-7):
//  - pc = x*190.0f; elevated = E @ pc (FMA chain); u = rint(ev/3) (IEEE div,
//    round-half-even). Integer tail exact: bin i = u0 - min_batch(u0).
__device__ __forceinline__ void compute_u(const float* __restrict__ x, int b, int n,
                                          int& u0o, int& u1o) {
    const float s6 = (float)2.449489742783178098197284074705891391989;
    const float ca = 2.0f / s6;
    const float cb = -1.0f / s6;
    const float* xb = x + (size_t)b * 6 * NPT + n;
    float p0 = xb[0 * NPT] * 190.0f;
    float p1 = xb[1 * NPT] * 190.0f;
    float p2 = xb[2 * NPT] * 190.0f;
    float ev0 = __builtin_fmaf(cb, p2, __builtin_fmaf(cb, p1, ca * p0));
    float ev1 = __builtin_fmaf(cb, p2, __builtin_fmaf(ca, p1, cb * p0));
    float ev2 = __builtin_fmaf(ca, p2, __builtin_fmaf(cb, p1, cb * p0));
    float q0 = ev0 / 3.0f, q1 = ev1 / 3.0f, q2 = ev2 / 3.0f;
    float rg0 = rintf(q0), rg1 = rintf(q1), rg2 = rintf(q2);  // half-even
    int u0 = (int)rg0, u1 = (int)rg1, u2 = (int)rg2;
    float e0 = ev0 - rg0 * 3.0f;
    float e1 = ev1 - rg1 * 3.0f;
    float e2 = ev2 - rg2 * 3.0f;
    int rk0 = (int)(e1 > e0) + (int)(e2 > e0);
    int rk1 = (int)(e0 > e1) + (int)(e0 == e1) + (int)(e2 > e1);
    int rs = u0 + u1 + u2;
    if (rs > 0) {
        if (rk0 >= 3 - rs) u0 -= 1;
        if (rk1 >= 3 - rs) u1 -= 1;
    } else if (rs < 0) {
        if (rk0 < -rs) u0 += 1;
        if (rk1 < -rs) u1 += 1;
    }
    u0o = u0; u1o = u1;
}

// One block per (batch, 32-row output stripe). Block scans ALL its batch's
// points (4x redundant -> exact local batch-min, zero inter-block deps),
// accumulates own-stripe survivors in an LDS tile, writes tile once with
// plain coalesced stores. No global zero pass, no global atomics, no ws.
__global__ __launch_bounds__(TPB, 4) void kone(const float* __restrict__ x,
                                               float* __restrict__ out) {
    const int wg = blockIdx.x;
    const int bid = ((wg & 7) << 5) | (wg >> 3);  // XCD co-location swizzle (perf only)
    const int b = bid >> 2, r = bid & 3;
    const int t = threadIdx.x;

    __shared__ float tile[TILE];
    __shared__ int red0[16], red1[16], osh[2];

    // zero own LDS tile
#pragma unroll
    for (int k = 0; k < TILE / TPB; ++k) tile[t + k * TPB] = 0.0f;

    // pass 1: all 8192 batch points; exact block-local batch min; stash u in regs
    int pk[PPT];
    int m0 = 0x7fffffff, m1 = 0x7fffffff;
#pragma unroll
    for (int k = 0; k < PPT; ++k) {
        int n = t + k * TPB;
        int u0, u1;
        compute_u(x, b, n, u0, u1);
        m0 = min(m0, u0);
        m1 = min(m1, u1);
        pk[k] = (u0 & 0xffff) | (u1 << 16);
    }
    for (int o = 32; o; o >>= 1) {
        m0 = min(m0, __shfl_down(m0, o));
        m1 = min(m1, __shfl_down(m1, o));
    }
    if ((t & 63) == 0) { red0[t >> 6] = m0; red1[t >> 6] = m1; }
    __syncthreads();
    if (t == 0) {
        int a0 = red0[0], a1 = red1[0];
#pragma unroll
        for (int i = 1; i < TPB / 64; ++i) { a0 = min(a0, red0[i]); a1 = min(a1, red1[i]); }
        osh[0] = a0; osh[1] = a1;
    }
    __syncthreads();
    const int off0 = osh[0], off1 = osh[1];
    const int rlo = r * ROWS;

    // pass 2: own-stripe survivors -> LDS atomics (i,j >= 0 always)
    const float* xb = x + (size_t)b * 6 * NPT;
#pragma unroll
    for (int k = 0; k < PPT; ++k) {
        int p = pk[k];
        int u0 = (int)(short)(p & 0xffff);
        int u1 = p >> 16;
        int i = u0 - off0, j = u1 - off1;
        int il = i - rlo;
        if ((unsigned)il < ROWS && (unsigned)j < GSZ) {
            int n = t + k * TPB;
            atomicAdd(&tile[0 * ROWS * GSZ + il * GSZ + j], xb[3 * NPT + n]);
            atomicAdd(&tile[1 * ROWS * GSZ + il * GSZ + j], xb[4 * NPT + n]);
            atomicAdd(&tile[2 * ROWS * GSZ + il * GSZ + j], xb[5 * NPT + n]);
        }
    }
    __syncthreads();

    // write own stripe once, fully coalesced: tile idx = c*4096 + il*128 + j
    // -> out[b*49152 + c*16384 + rlo*128 + (idx % 4096)]
    float* ob = out + (size_t)b * 3 * GSZ * GSZ + rlo * GSZ;
#pragma unroll
    for (int k = 0; k < TILE / TPB; ++k) {
        int idx = t + k * TPB;
        int c = idx >> 12;
        ob[c * GSZ * GSZ + (idx & 4095)] = tile[idx];
    }
}

extern "C" void kernel_launch(void* const* d_in, const int* in_sizes, int n_in,
                              void* d_out, int out_size, void* d_ws, size_t ws_size,
                              hipStream_t stream) {
    const float* x = (const float*)d_in[0];
    float* out = (float*)d_out;
    kone<<<NBLK, TPB, 0, stream>>>(x, out);
}

// Round 9
// 13.629 us; speedup vs baseline: 2.8643x; 1.0423x over previous
//
#include <hip/hip_runtime.h>

#define NB    64
#define NPT   8192
#define GSZ   128
#define TPB   1024
#define BPB   4                       // blocks per batch
#define NBLK  (NB * BPB)              // 256 = 1 block/CU, full chip
#define ROWS  32                      // output stripe rows per block
#define TILE  (3 * ROWS * GSZ)        // 12288 floats = 48 KB LDS

// Per-point permutohedral math. Bitwise-replicates XLA-CPU f32 (verified
// absmax == 0.0 rounds 1-8): pc = v*190.0f; elevated = E @ pc (FMA chain);
// u = rint(ev/3) (IEEE div, round-half-even); exact integer fixup.
__device__ __forceinline__ void compute_pt(float v0, float v1, float v2,
                                           int& u0o, int& u1o) {
    const float s6 = (float)2.449489742783178098197284074705891391989;
    const float ca = 2.0f / s6;
    const float cb = -1.0f / s6;
    float p0 = v0 * 190.0f;
    float p1 = v1 * 190.0f;
    float p2 = v2 * 190.0f;
    float ev0 = __builtin_fmaf(cb, p2, __builtin_fmaf(cb, p1, ca * p0));
    float ev1 = __builtin_fmaf(cb, p2, __builtin_fmaf(ca, p1, cb * p0));
    float ev2 = __builtin_fmaf(ca, p2, __builtin_fmaf(cb, p1, cb * p0));
    float q0 = ev0 / 3.0f, q1 = ev1 / 3.0f, q2 = ev2 / 3.0f;
    float rg0 = rintf(q0), rg1 = rintf(q1), rg2 = rintf(q2);  // half-even
    int u0 = (int)rg0, u1 = (int)rg1, u2 = (int)rg2;
    float e0 = ev0 - rg0 * 3.0f;   // 3*rg exact (<2^24) -> correctly-rounded sub
    float e1 = ev1 - rg1 * 3.0f;
    float e2 = ev2 - rg2 * 3.0f;
    int rk0 = (int)(e1 > e0) + (int)(e2 > e0);
    int rk1 = (int)(e0 > e1) + (int)(e0 == e1) + (int)(e2 > e1);
    int rs = u0 + u1 + u2;
    if (rs > 0) {
        if (rk0 >= 3 - rs) u0 -= 1;
        if (rk1 >= 3 - rs) u1 -= 1;
    } else if (rs < 0) {
        if (rk0 < -rs) u0 += 1;
        if (rk1 < -rs) u1 += 1;
    }
    u0o = u0; u1o = u1;
}

// One block per (batch, 32-row output stripe). Block scans ALL its batch's
// points (exact local batch-min, zero inter-block deps), accumulates
// own-stripe survivors in an LDS tile, writes the tile once, coalesced.
// No global zero pass, no global atomics, no fences, no ws.
__global__ __launch_bounds__(TPB, 4) void kone(const float* __restrict__ x,
                                               float* __restrict__ out) {
    const int wg = blockIdx.x;
    const int bid = ((wg & 7) << 5) | (wg >> 3);  // XCD co-location swizzle (perf only)
    const int b = bid >> 2, r = bid & 3;
    const int t = threadIdx.x;

    __shared__ float tile[TILE];
    __shared__ int red0[16], red1[16], osh[2];

    // zero own LDS tile (float4: 3 ds_write_b128 per thread)
    float4* tile4 = (float4*)tile;
    const float4 z4 = make_float4(0.f, 0.f, 0.f, 0.f);
#pragma unroll
    for (int k = 0; k < TILE / 4 / TPB; ++k) tile4[t + k * TPB] = z4;

    // pass 1: all 8192 batch points, float4 position loads (4 consecutive
    // points per thread x 2 groups); exact block-local batch min; stash u.
    const float* xb = x + (size_t)b * 6 * NPT;
    int pk[8];
    int m0 = 0x7fffffff, m1 = 0x7fffffff;
#pragma unroll
    for (int g = 0; g < 2; ++g) {
        const int n = 4 * t + g * 4096;
        const float4 P0 = *(const float4*)(xb + n);
        const float4 P1 = *(const float4*)(xb + NPT + n);
        const float4 P2 = *(const float4*)(xb + 2 * NPT + n);
        const float* f0 = (const float*)&P0;
        const float* f1 = (const float*)&P1;
        const float* f2 = (const float*)&P2;
#pragma unroll
        for (int e = 0; e < 4; ++e) {
            int u0, u1;
            compute_pt(f0[e], f1[e], f2[e], u0, u1);
            m0 = min(m0, u0);
            m1 = min(m1, u1);
            pk[g * 4 + e] = (u0 & 0xffff) | (u1 << 16);
        }
    }
    for (int o = 32; o; o >>= 1) {
        m0 = min(m0, __shfl_down(m0, o));
        m1 = min(m1, __shfl_down(m1, o));
    }
    if ((t & 63) == 0) { red0[t >> 6] = m0; red1[t >> 6] = m1; }
    __syncthreads();
    if (t == 0) {
        int a0 = red0[0], a1 = red1[0];
#pragma unroll
        for (int i = 1; i < TPB / 64; ++i) { a0 = min(a0, red0[i]); a1 = min(a1, red1[i]); }
        osh[0] = a0; osh[1] = a1;
    }
    __syncthreads();
    const int off0 = osh[0], off1 = osh[1];
    const int rlo = r * ROWS;

    // pass 2: own-stripe survivors -> LDS atomics (sparse, ~0.5%)
#pragma unroll
    for (int k = 0; k < 8; ++k) {
        int p = pk[k];
        int u0 = (int)(short)(p & 0xffff);
        int u1 = p >> 16;
        int i = u0 - off0, j = u1 - off1;   // >= 0 always
        int il = i - rlo;
        if ((unsigned)il < ROWS && (unsigned)j < GSZ) {
            int n = 4 * t + (k >> 2) * 4096 + (k & 3);
            atomicAdd(&tile[0 * ROWS * GSZ + il * GSZ + j], xb[3 * NPT + n]);
            atomicAdd(&tile[1 * ROWS * GSZ + il * GSZ + j], xb[4 * NPT + n]);
            atomicAdd(&tile[2 * ROWS * GSZ + il * GSZ + j], xb[5 * NPT + n]);
        }
    }
    __syncthreads();

    // write own stripe once (float4, fully coalesced): channel planes are
    // contiguous both in LDS (tile4[c*1024..]) and in global (ob + c*128*128).
    float* ob = out + (size_t)b * 3 * GSZ * GSZ + rlo * GSZ;
#pragma unroll
    for (int c = 0; c < 3; ++c)
        ((float4*)(ob + c * GSZ * GSZ))[t] = tile4[c * 1024 + t];
}

extern "C" void kernel_launch(void* const* d_in, const int* in_sizes, int n_in,
                              void* d_out, int out_size, void* d_ws, size_t ws_size,
                              hipStream_t stream) {
    const float* x = (const float*)d_in[0];
    float* out = (float*)d_out;
    kone<<<NBLK, TPB, 0, stream>>>(x, out);
}

// Round 11
// 11.442 us; speedup vs baseline: 3.4117x; 1.1911x over previous
//
#include <hip/hip_runtime.h>

#define NB    64
#define NPT   8192
#define GSZ   128
#define TPB   1024
#define BPB   4                       // blocks per batch
#define NBLK  (NB * BPB)              // 256 = 1 block/CU, full chip
#define ROWS  32                      // output stripe rows per block
#define TILE  (3 * ROWS * GSZ)        // 12288 floats = 48 KB LDS

typedef float vf4 __attribute__((ext_vector_type(4)));  // native vec for NT stores

// Per-point permutohedral math. Bitwise-replicates XLA-CPU f32 (verified
// absmax == 0.0 rounds 1-9): pc = v*190.0f; elevated = E @ pc (FMA chain);
// u = rint(ev/3) (round-half-even); exact integer fixup.
// ev/3 computed via Markstein constant-division (q0=ev*y; r=fma(-3,q0,ev);
// q=fma(r,y,q0), y=RN(1/3)) — correctly rounded for all binary32 ev
// (classic verified-constant case), i.e. bit-identical to v_div IEEE /3.
__device__ __forceinline__ void compute_pt(float v0, float v1, float v2,
                                           int& u0o, int& u1o) {
    const float s6 = (float)2.449489742783178098197284074705891391989;
    const float ca = 2.0f / s6;
    const float cb = -1.0f / s6;
    const float y3 = 0.333333343267440796f;   // 0x3EAAAAAB = RN(1/3)
    float p0 = v0 * 190.0f;
    float p1 = v1 * 190.0f;
    float p2 = v2 * 190.0f;
    float ev0 = __builtin_fmaf(cb, p2, __builtin_fmaf(cb, p1, ca * p0));
    float ev1 = __builtin_fmaf(cb, p2, __builtin_fmaf(ca, p1, cb * p0));
    float ev2 = __builtin_fmaf(ca, p2, __builtin_fmaf(cb, p1, cb * p0));
    float t0 = ev0 * y3, t1 = ev1 * y3, t2 = ev2 * y3;
    float q0 = __builtin_fmaf(__builtin_fmaf(-3.0f, t0, ev0), y3, t0);
    float q1 = __builtin_fmaf(__builtin_fmaf(-3.0f, t1, ev1), y3, t1);
    float q2 = __builtin_fmaf(__builtin_fmaf(-3.0f, t2, ev2), y3, t2);
    float rg0 = rintf(q0), rg1 = rintf(q1), rg2 = rintf(q2);  // half-even
    int u0 = (int)rg0, u1 = (int)rg1, u2 = (int)rg2;
    float e0 = ev0 - rg0 * 3.0f;   // exact (moderate range)
    float e1 = ev1 - rg1 * 3.0f;
    float e2 = ev2 - rg2 * 3.0f;
    int rk0 = (int)(e1 > e0) + (int)(e2 > e0);
    int rk1 = (int)(e0 >= e1) + (int)(e2 > e1);   // (>)+(==) folded
    int rs = u0 + u1 + u2;
    if (rs > 0) {
        if (rk0 >= 3 - rs) u0 -= 1;
        if (rk1 >= 3 - rs) u1 -= 1;
    } else if (rs < 0) {
        if (rk0 < -rs) u0 += 1;
        if (rk1 < -rs) u1 += 1;
    }
    u0o = u0; u1o = u1;
}

// One block per (batch, 32-row output stripe). Block scans ALL its batch's
// points (exact local batch-min, zero inter-block deps), accumulates
// own-stripe survivors in an LDS tile, writes the tile once, coalesced.
// No global zero pass, no global atomics, no fences, no ws.
__global__ __launch_bounds__(TPB, 4) void kone(const float* __restrict__ x,
                                               float* __restrict__ out) {
    const int wg = blockIdx.x;
    const int bid = ((wg & 7) << 5) | (wg >> 3);  // XCD co-location swizzle (perf only)
    const int b = bid >> 2, r = bid & 3;
    const int t = threadIdx.x;

    __shared__ float tile[TILE];
    __shared__ int red0[16], red1[16], osh[2];

    // zero own LDS tile (3 ds_write_b128 per thread)
    float4* tile4 = (float4*)tile;
    const float4 z4 = make_float4(0.f, 0.f, 0.f, 0.f);
#pragma unroll
    for (int k = 0; k < TILE / 4 / TPB; ++k) tile4[t + k * TPB] = z4;

    // pass 1: all 8192 batch points; issue ALL 12 float4 position loads up
    // front (latency fully overlapped with compute), then exact local min.
    const float* xb = x + (size_t)b * 6 * NPT;
    const int n0 = 4 * t, n1 = 4 * t + 4096;
    const float4 A0 = *(const float4*)(xb + n0);
    const float4 A1 = *(const float4*)(xb + NPT + n0);
    const float4 A2 = *(const float4*)(xb + 2 * NPT + n0);
    const float4 B0 = *(const float4*)(xb + n1);
    const float4 B1 = *(const float4*)(xb + NPT + n1);
    const float4 B2 = *(const float4*)(xb + 2 * NPT + n1);

    int pk[8];
    int m0 = 0x7fffffff, m1 = 0x7fffffff;
    {
        const float* f0 = (const float*)&A0;
        const float* f1 = (const float*)&A1;
        const float* f2 = (const float*)&A2;
#pragma unroll
        for (int e = 0; e < 4; ++e) {
            int u0, u1;
            compute_pt(f0[e], f1[e], f2[e], u0, u1);
            m0 = min(m0, u0); m1 = min(m1, u1);
            pk[e] = (u0 & 0xffff) | (u1 << 16);
        }
    }
    {
        const float* f0 = (const float*)&B0;
        const float* f1 = (const float*)&B1;
        const float* f2 = (const float*)&B2;
#pragma unroll
        for (int e = 0; e < 4; ++e) {
            int u0, u1;
            compute_pt(f0[e], f1[e], f2[e], u0, u1);
            m0 = min(m0, u0); m1 = min(m1, u1);
            pk[4 + e] = (u0 & 0xffff) | (u1 << 16);
        }
    }
    for (int o = 32; o; o >>= 1) {
        m0 = min(m0, __shfl_down(m0, o));
        m1 = min(m1, __shfl_down(m1, o));
    }
    if ((t & 63) == 0) { red0[t >> 6] = m0; red1[t >> 6] = m1; }
    __syncthreads();
    if (t == 0) {
        int a0 = red0[0], a1 = red1[0];
#pragma unroll
        for (int i = 1; i < TPB / 64; ++i) { a0 = min(a0, red0[i]); a1 = min(a1, red1[i]); }
        osh[0] = a0; osh[1] = a1;
    }
    __syncthreads();
    const int off0 = osh[0], off1 = osh[1];
    const int rlo = r * ROWS;

    // pass 2: own-stripe survivors -> LDS atomics (sparse, ~0.2%)
#pragma unroll
    for (int k = 0; k < 8; ++k) {
        int p = pk[k];
        int u0 = (int)(short)(p & 0xffff);
        int u1 = p >> 16;
        int i = u0 - off0, j = u1 - off1;   // >= 0 always
        int il = i - rlo;
        if ((unsigned)il < ROWS && (unsigned)j < GSZ) {
            int n = 4 * t + (k >> 2) * 4096 + (k & 3);
            atomicAdd(&tile[0 * ROWS * GSZ + il * GSZ + j], xb[3 * NPT + n]);
            atomicAdd(&tile[1 * ROWS * GSZ + il * GSZ + j], xb[4 * NPT + n]);
            atomicAdd(&tile[2 * ROWS * GSZ + il * GSZ + j], xb[5 * NPT + n]);
        }
    }
    __syncthreads();

    // write own stripe once (nontemporal, fully coalesced; native vec type)
    float* ob = out + (size_t)b * 3 * GSZ * GSZ + rlo * GSZ;
    const vf4* tilev = (const vf4*)tile;
#pragma unroll
    for (int c = 0; c < 3; ++c)
        __builtin_nontemporal_store(tilev[c * 1024 + t], &((vf4*)(ob + c * GSZ * GSZ))[t]);
}

extern "C" void kernel_launch(void* const* d_in, const int* in_sizes, int n_in,
                              void* d_out, int out_size, void* d_ws, size_t ws_size,
                              hipStream_t stream) {
    const float* x = (const float*)d_in[0];
    float* out = (float*)d_out;
    kone<<<NBLK, TPB, 0, stream>>>(x, out);
}